// Round 6
// baseline (152.215 us; speedup 1.0000x reference)
//
#include <hip/hip_runtime.h>
#include <hip/hip_bf16.h>
#include <hip/hip_fp16.h>

// ---------------------------------------------------------------------------
// Multihead attention with flat-reshape head split + mean-threshold mask.
//   B=8 S=1024 D=512 H=8 -> 64 independent attention problems of (1024 x 64);
//   problem (h,b) = 128 consecutive rows of the 8192x512 projected matrix
//   reinterpreted as 1024x64.
// Precision: Q/K path 3-term bf16 split -> fp32-accurate scores. V/P/O fp16.
// Round-6:
//   * k_attn: LDS double-buffer (ONE barrier/chunk, was 2), den accumulated
//     via ones-column MFMA (no per-score VALU add, no end shuffles), Q
//     pre-scaled by kNorm*log2e at projection -> per-score cost = cmp +
//     v_exp + cndmask + cvt.
//   * k_split: x,y -> bf16 hi/lo once (memory-bound pre-pass); projection
//     GEMM stages via pure vector loads (round-5 did 16 splitbf/thread/kstep
//     inside the MFMA loop).
//   * k_proj: Q,K (split bf16, 3-term) and V (fp16) projections merged into
//     ONE dispatch (768 blocks = 3/CU; were 2 serialized dispatches at 1/CU).
// ---------------------------------------------------------------------------

typedef _Float16 f16;
typedef __attribute__((ext_vector_type(4))) _Float16 f16x4;
typedef __attribute__((ext_vector_type(8))) _Float16 f16x8;
typedef __attribute__((ext_vector_type(8))) short bf16x8;
typedef __attribute__((ext_vector_type(4))) float f32x4;

#define MFMA16(a, b, c) __builtin_amdgcn_mfma_f32_16x16x32_f16((a), (b), (c), 0, 0, 0)
#define MFMAB16(a, b, c) __builtin_amdgcn_mfma_f32_16x16x32_bf16((a), (b), (c), 0, 0, 0)
#define MFMAPV(a, b, c) __builtin_amdgcn_mfma_f32_16x16x16f16((a), (b), (c), 0, 0, 0)

// exp strategy: if the direct 2^x builtin exists, fold kNorm*log2e into Q at
// projection time and use exp2 (1 trans op); else fold kNorm only, use __expf.
#if defined(__has_builtin) && __has_builtin(__builtin_amdgcn_exp2f)
#define EXPFN(x) __builtin_amdgcn_exp2f(x)
#define QPROJ_SCALE (0.04419417382415922f * 1.4426950408889634f)
#else
#define EXPFN(x) __expf(x)
#define QPROJ_SCALE 0.04419417382415922f
#endif

__device__ __forceinline__ float b2f(short s) {
  return __uint_as_float(((unsigned)(unsigned short)s) << 16);
}

// float -> (bf16 hi, bf16 lo) with RNE via __float2bfloat16
__device__ __forceinline__ void splitbf(float v, short& h, short& l) {
  unsigned short hu = __bfloat16_as_ushort(__float2bfloat16(v));
  h = (short)hu;
  float hf = __uint_as_float(((unsigned)hu) << 16);
  l = (short)__bfloat16_as_ushort(__float2bfloat16(v - hf));
}

// --------------------------- weight transpose+convert ----------------------
__global__ void k_wt(const float* __restrict__ w0, const float* __restrict__ w1,
                     const float* __restrict__ w2, const float* __restrict__ w3,
                     short* __restrict__ qh, short* __restrict__ ql,
                     short* __restrict__ kh, short* __restrict__ kl,
                     f16* __restrict__ vt, f16* __restrict__ ot) {
  const float* W;
  switch (blockIdx.z) {
    case 0: W = w0; break;
    case 1: W = w1; break;
    case 2: W = w2; break;
    default: W = w3; break;
  }
  __shared__ float t[32][33];
  int bx = blockIdx.x, by = blockIdx.y;
  int tx = threadIdx.x, ty = threadIdx.y;  // 32 x 8
#pragma unroll
  for (int i = 0; i < 32; i += 8)
    t[ty + i][tx] = W[(size_t)(by * 32 + ty + i) * 512 + bx * 32 + tx];
  __syncthreads();
#pragma unroll
  for (int i = 0; i < 32; i += 8) {
    size_t idx = (size_t)(bx * 32 + ty + i) * 512 + by * 32 + tx;
    float v = t[tx][ty + i];
    if (blockIdx.z < 2) {
      short h, l;
      splitbf(v, h, l);
      if (blockIdx.z == 0) { qh[idx] = h; ql[idx] = l; }
      else { kh[idx] = h; kl[idx] = l; }
    } else {
      if (blockIdx.z == 2) vt[idx] = (f16)v;
      else ot[idx] = (f16)v;
    }
  }
}

// ----------------------- input split (x,y -> bf16 hi/lo) -------------------
__global__ __launch_bounds__(256) void k_split(
    const float* __restrict__ x, const float* __restrict__ y,
    short* __restrict__ Xh, short* __restrict__ Xl, short* __restrict__ Yh,
    short* __restrict__ Yl) {
  const float* src = blockIdx.y ? y : x;
  short* dh = blockIdx.y ? Yh : Xh;
  short* dl = blockIdx.y ? Yl : Xl;
  const size_t i = ((size_t)blockIdx.x * 256 + threadIdx.x) * 8;
  float4 a = *(const float4*)(src + i);
  float4 b = *(const float4*)(src + i + 4);
  float v[8] = {a.x, a.y, a.z, a.w, b.x, b.y, b.z, b.w};
  bf16x8 h, l;
#pragma unroll
  for (int j = 0; j < 8; ++j) {
    short hh, ll;
    splitbf(v[j], hh, ll);
    h[j] = hh;
    l[j] = ll;
  }
  *(bf16x8*)(dh + i) = h;
  *(bf16x8*)(dl + i) = l;
}

// ------------------------- plain fp16 GEMM body ----------------------------
template <typename AT, typename OT>
__device__ __forceinline__ void gemm_body(const AT* __restrict__ A,
                                          const f16* __restrict__ WT,
                                          const float* __restrict__ bias,
                                          OT* __restrict__ C, int m0, int n0,
                                          f16 (*As)[40], f16 (*Bs)[40]) {
  const int tid = threadIdx.x;
  const int wv = tid >> 6, lane = tid & 63;
  const int wm = wv >> 1, wn = wv & 1;
  const int l15 = lane & 15, lg = lane >> 4;
  const int sr = tid >> 1, sc = (tid & 1) * 16;

  const f32x4 fzero = {0.f, 0.f, 0.f, 0.f};
  f32x4 acc[4][4];
#pragma unroll
  for (int m = 0; m < 4; ++m)
#pragma unroll
    for (int n = 0; n < 4; ++n) acc[m][n] = fzero;

  for (int k0 = 0; k0 < 512; k0 += 32) {
    if constexpr (sizeof(AT) == 4) {
      const float* src = (const float*)A + (size_t)(m0 + sr) * 512 + k0 + sc;
      float4 a0 = *(const float4*)(src + 0);
      float4 a1 = *(const float4*)(src + 4);
      float4 a2 = *(const float4*)(src + 8);
      float4 a3 = *(const float4*)(src + 12);
      f16* d = &As[sr][sc];
      d[0] = (f16)a0.x; d[1] = (f16)a0.y; d[2] = (f16)a0.z; d[3] = (f16)a0.w;
      d[4] = (f16)a1.x; d[5] = (f16)a1.y; d[6] = (f16)a1.z; d[7] = (f16)a1.w;
      d[8] = (f16)a2.x; d[9] = (f16)a2.y; d[10] = (f16)a2.z; d[11] = (f16)a2.w;
      d[12] = (f16)a3.x; d[13] = (f16)a3.y; d[14] = (f16)a3.z; d[15] = (f16)a3.w;
    } else {
      const f16* src = (const f16*)A + (size_t)(m0 + sr) * 512 + k0 + sc;
      *(f16x8*)&As[sr][sc] = *(const f16x8*)src;
      *(f16x8*)&As[sr][sc + 8] = *(const f16x8*)(src + 8);
    }
    {
      const f16* src = WT + (size_t)(n0 + sr) * 512 + k0 + sc;
      *(f16x8*)&Bs[sr][sc] = *(const f16x8*)src;
      *(f16x8*)&Bs[sr][sc + 8] = *(const f16x8*)(src + 8);
    }
    __syncthreads();
    f16x8 af[4], bf[4];
#pragma unroll
    for (int m = 0; m < 4; ++m)
      af[m] = *(const f16x8*)&As[wm * 64 + m * 16 + l15][lg * 8];
#pragma unroll
    for (int n = 0; n < 4; ++n)
      bf[n] = *(const f16x8*)&Bs[wn * 64 + n * 16 + l15][lg * 8];
#pragma unroll
    for (int m = 0; m < 4; ++m)
#pragma unroll
      for (int n = 0; n < 4; ++n) acc[m][n] = MFMA16(af[m], bf[n], acc[m][n]);
    __syncthreads();
  }
#pragma unroll
  for (int n = 0; n < 4; ++n) {
    const int col = n0 + wn * 64 + n * 16 + l15;
    const float b = bias[col];
#pragma unroll
    for (int m = 0; m < 4; ++m) {
      const int row = m0 + wm * 64 + m * 16 + lg * 4;
#pragma unroll
      for (int r = 0; r < 4; ++r) {
        float v = acc[m][n][r] + b;
        C[(size_t)(row + r) * 512 + col] = (OT)v;
      }
    }
  }
}

__global__ __launch_bounds__(256) void k_gemm_out(const f16* __restrict__ Om,
                                                  const f16* __restrict__ owT,
                                                  const float* __restrict__ ob,
                                                  float* __restrict__ out) {
  __shared__ __align__(16) f16 As[128][40];
  __shared__ __align__(16) f16 Bs[128][40];
  gemm_body<f16, float>(Om, owT, ob, out, blockIdx.y * 128, blockIdx.x * 128,
                        As, Bs);
}

// ---------------- merged projections: Q,K (split) + V (fp16) ---------------
__global__ __launch_bounds__(256) void k_proj(
    const short* __restrict__ Xh, const short* __restrict__ Xl,
    const short* __restrict__ Yh, const short* __restrict__ Yl,
    const float* __restrict__ y, const short* __restrict__ qwh,
    const short* __restrict__ qwl, const short* __restrict__ kwh,
    const short* __restrict__ kwl, const f16* __restrict__ vwT,
    const float* __restrict__ qb, const float* __restrict__ kbias,
    const float* __restrict__ vb, short* __restrict__ Qh,
    short* __restrict__ Ql, short* __restrict__ Kh, short* __restrict__ Kl,
    f16* __restrict__ Vm) {
  __shared__ __align__(16) short sm4[4][128][40];  // 40 KB
  const int m0 = blockIdx.y * 128, n0 = blockIdx.x * 128;
  if (blockIdx.z == 2) {
    gemm_body<float, f16>(y, vwT, vb, Vm, m0, n0, (f16(*)[40]) & sm4[0][0][0],
                          (f16(*)[40]) & sm4[1][0][0]);
    return;
  }
  const int z = blockIdx.z;
  const short* Agh = z ? Yh : Xh;
  const short* Agl = z ? Yl : Xl;
  const short* Wh = z ? kwh : qwh;
  const short* Wl = z ? kwl : qwl;
  const float* bias = z ? kbias : qb;
  short* Ch = z ? Kh : Qh;
  short* Cl = z ? Kl : Ql;
  const float osc = z ? 1.f : (float)QPROJ_SCALE;  // Q pre-scaled for attn

  short(*Ah)[40] = sm4[0];
  short(*Al)[40] = sm4[1];
  short(*Bh)[40] = sm4[2];
  short(*Bl)[40] = sm4[3];
  const int tid = threadIdx.x;
  const int wv = tid >> 6, lane = tid & 63;
  const int wm = wv >> 1, wn = wv & 1;
  const int l15 = lane & 15, lg = lane >> 4;
  const int sr = tid >> 1, sc = (tid & 1) * 16;

  const f32x4 fzero = {0.f, 0.f, 0.f, 0.f};
  f32x4 acc[4][4];
#pragma unroll
  for (int m = 0; m < 4; ++m)
#pragma unroll
    for (int n = 0; n < 4; ++n) acc[m][n] = fzero;

  for (int k0 = 0; k0 < 512; k0 += 32) {
    {
      const size_t o = (size_t)(m0 + sr) * 512 + k0 + sc;
      *(bf16x8*)&Ah[sr][sc] = *(const bf16x8*)(Agh + o);
      *(bf16x8*)&Ah[sr][sc + 8] = *(const bf16x8*)(Agh + o + 8);
      *(bf16x8*)&Al[sr][sc] = *(const bf16x8*)(Agl + o);
      *(bf16x8*)&Al[sr][sc + 8] = *(const bf16x8*)(Agl + o + 8);
    }
    {
      const size_t o = (size_t)(n0 + sr) * 512 + k0 + sc;
      *(bf16x8*)&Bh[sr][sc] = *(const bf16x8*)(Wh + o);
      *(bf16x8*)&Bh[sr][sc + 8] = *(const bf16x8*)(Wh + o + 8);
      *(bf16x8*)&Bl[sr][sc] = *(const bf16x8*)(Wl + o);
      *(bf16x8*)&Bl[sr][sc + 8] = *(const bf16x8*)(Wl + o + 8);
    }
    __syncthreads();
    bf16x8 afh[4], afl[4], bfh[4], bfl[4];
#pragma unroll
    for (int m = 0; m < 4; ++m) {
      afh[m] = *(const bf16x8*)&Ah[wm * 64 + m * 16 + l15][lg * 8];
      afl[m] = *(const bf16x8*)&Al[wm * 64 + m * 16 + l15][lg * 8];
    }
#pragma unroll
    for (int n = 0; n < 4; ++n) {
      bfh[n] = *(const bf16x8*)&Bh[wn * 64 + n * 16 + l15][lg * 8];
      bfl[n] = *(const bf16x8*)&Bl[wn * 64 + n * 16 + l15][lg * 8];
    }
#pragma unroll
    for (int m = 0; m < 4; ++m)
#pragma unroll
      for (int n = 0; n < 4; ++n) {
        acc[m][n] = MFMAB16(afh[m], bfh[n], acc[m][n]);
        acc[m][n] = MFMAB16(afh[m], bfl[n], acc[m][n]);
        acc[m][n] = MFMAB16(afl[m], bfh[n], acc[m][n]);
      }
    __syncthreads();
  }
#pragma unroll
  for (int n = 0; n < 4; ++n) {
    const int col = n0 + wn * 64 + n * 16 + l15;
    const float b = bias[col];
#pragma unroll
    for (int m = 0; m < 4; ++m) {
      const int row = m0 + wm * 64 + m * 16 + lg * 4;
#pragma unroll
      for (int r = 0; r < 4; ++r) {
        float v = (acc[m][n][r] + b) * osc;
        short h, l;
        splitbf(v, h, l);
        const size_t idx = (size_t)(row + r) * 512 + col;
        Ch[idx] = h;
        Cl[idx] = l;
      }
    }
  }
}

// ----------------------- V transpose (per problem) -------------------------
// Vm [8192][512] f16 -> Vt [64 p][64 dh][1024 k] f16.
__global__ __launch_bounds__(256) void k_vtr(const f16* __restrict__ Vm,
                                             f16* __restrict__ Vt) {
  const int p = blockIdx.y;
  const int j0 = blockIdx.x * 16;
  __shared__ f16 L[16][520];
  const int tid = threadIdx.x;
#pragma unroll
  for (int it = 0; it < 4; ++it) {
    int idx = it * 256 + tid;
    int row = idx >> 6, oct = idx & 63;
    *(f16x8*)&L[row][oct * 8] =
        *(const f16x8*)&Vm[(size_t)(p * 128 + j0 + row) * 512 + oct * 8];
  }
  __syncthreads();
#pragma unroll
  for (int it = 0; it < 4; ++it) {
    int idx = it * 256 + tid;
    int dh = idx >> 4, j = idx & 15;
    f16x8 v;
#pragma unroll
    for (int g = 0; g < 8; ++g) v[g] = L[j][g * 64 + dh];
    *(f16x8*)&Vt[((size_t)p * 64 + dh) * 1024 + (j0 + j) * 8] = v;
  }
}

// ------------------- K column-mean (for mean-threshold) --------------------
__global__ __launch_bounds__(256) void k_kmean(const short* __restrict__ Kh,
                                               const short* __restrict__ Kl,
                                               float* __restrict__ Kmean) {
  const int p = blockIdx.x;
  const int t = threadIdx.x;
  const int dh = t & 63, kg = t >> 6;
  const short* hp = Kh + (size_t)p * 65536 + dh;
  const short* lp = Kl + (size_t)p * 65536 + dh;
  float s = 0.f;
  for (int k = kg * 256; k < (kg + 1) * 256; ++k)
    s += b2f(hp[(size_t)k * 64]) + b2f(lp[(size_t)k * 64]);
  __shared__ float red[4][64];
  red[kg][dh] = s;
  __syncthreads();
  if (t < 64)
    Kmean[p * 64 + t] =
        (red[0][t] + red[1][t] + red[2][t] + red[3][t]) * (1.f / 1024.f);
}

// ------------------------------- attention ---------------------------------
// grid (64 problems [fast], 8 q-tiles), 256 threads = 4 waves, 32 q/wave.
// Double-buffered LDS (48 KB): ONE barrier per 64-key chunk. Register
// prefetch 2 chunks ahead. Q pre-scaled by QPROJ_SCALE -> per-score cost:
// cmp + exp + cndmask + cvt. den via ones-column MFMA (no VALU adds).
#define LOADREG(cc)                            \
  {                                            \
    const int off = (cc)*4096;                 \
    rh0 = *(const bf16x8*)(KhSrc + off);       \
    rh1 = *(const bf16x8*)(KhSrc + off + 8);   \
    rl0 = *(const bf16x8*)(KlSrc + off);       \
    rl1 = *(const bf16x8*)(KlSrc + off + 8);   \
    rv0 = *(const f16x8*)(VSrc + (cc)*64);     \
    rv1 = *(const f16x8*)(VSrc + (cc)*64 + 8); \
  }
#define STOREBUF(b)                        \
  {                                        \
    *(bf16x8*)&KhS[b][skey][sslot0] = rh0; \
    *(bf16x8*)&KhS[b][skey][sslot1] = rh1; \
    *(bf16x8*)&KlS[b][skey][sslot0] = rl0; \
    *(bf16x8*)&KlS[b][skey][sslot1] = rl1; \
    *(f16x8*)&Vs[b][skey][sslot0] = rv0;   \
    *(f16x8*)&Vs[b][skey][sslot1] = rv1;   \
  }

__global__ __launch_bounds__(256, 2) void k_attn(
    const short* __restrict__ Qh, const short* __restrict__ Ql,
    const short* __restrict__ Kh, const short* __restrict__ Kl,
    const f16* __restrict__ Vt, const float* __restrict__ Kmean,
    f16* __restrict__ Om) {
  constexpr int S = 1024, DH = 64;
  const int p = blockIdx.x;
  const int qt = blockIdx.y;
  const size_t pb = (size_t)p * S * DH;
  const short* Qhp = Qh + pb;
  const short* Qlp = Ql + pb;
  const short* Khp = Kh + pb;
  const short* Klp = Kl + pb;
  const f16* Vtp = Vt + pb;  // [64 dh][1024 k]
  f16* Op = Om + pb;

  const int tid = threadIdx.x;
  const int w = tid >> 6, lane = tid & 63;
  const int l15 = lane & 15, lg = lane >> 4;

  __shared__ __align__(16) short KhS[2][64][64];
  __shared__ __align__(16) short KlS[2][64][64];
  __shared__ __align__(16) f16 Vs[2][64][64];  // 48 KB total

  const int skey = tid >> 2;
  const int s2 = (tid & 3) * 2;
  const int ssw = skey & 7;
  const int sslot0 = (s2 ^ ssw) * 8;
  const int sslot1 = ((s2 + 1) ^ ssw) * 8;
  const short* KhSrc = Khp + skey * 64 + (tid & 3) * 16;
  const short* KlSrc = Klp + skey * 64 + (tid & 3) * 16;
  const f16* VSrc = Vtp + (size_t)skey * 1024 + (tid & 3) * 16;

  bf16x8 rh0, rh1, rl0, rl1;
  f16x8 rv0, rv1;
  LOADREG(0);
  STOREBUF(0);  // visible to all after iter-0 barrier
  LOADREG(1);

  // Q B-frags, two q-groups (Q pre-scaled by QPROJ_SCALE)
  const int qb = qt * 128 + w * 32;
  const size_t qo0 = (size_t)(qb + l15) * DH + lg * 8;
  const size_t qo1 = (size_t)(qb + 16 + l15) * DH + lg * 8;
  bf16x8 q0h0 = *(const bf16x8*)(Qhp + qo0);
  bf16x8 q0l0 = *(const bf16x8*)(Qlp + qo0);
  bf16x8 q0h1 = *(const bf16x8*)(Qhp + qo0 + 32);
  bf16x8 q0l1 = *(const bf16x8*)(Qlp + qo0 + 32);
  bf16x8 q1h0 = *(const bf16x8*)(Qhp + qo1);
  bf16x8 q1l0 = *(const bf16x8*)(Qlp + qo1);
  bf16x8 q1h1 = *(const bf16x8*)(Qhp + qo1 + 32);
  bf16x8 q1l1 = *(const bf16x8*)(Qlp + qo1 + 32);

  // threshold: mean_q = Qscaled_q . Kmean (consistent scale with scores)
  const float* kmp = Kmean + p * 64;
  float4 km0a = *(const float4*)(kmp + lg * 8);
  float4 km0b = *(const float4*)(kmp + lg * 8 + 4);
  float4 km1a = *(const float4*)(kmp + 32 + lg * 8);
  float4 km1b = *(const float4*)(kmp + 32 + lg * 8 + 4);
  float km0[8] = {km0a.x, km0a.y, km0a.z, km0a.w,
                  km0b.x, km0b.y, km0b.z, km0b.w};
  float km1[8] = {km1a.x, km1a.y, km1a.z, km1a.w,
                  km1b.x, km1b.y, km1b.z, km1b.w};
  float sm0 = 0.f, sm1 = 0.f;
#pragma unroll
  for (int j = 0; j < 8; ++j) {
    sm0 += (b2f(q0h0[j]) + b2f(q0l0[j])) * km0[j] +
           (b2f(q0h1[j]) + b2f(q0l1[j])) * km1[j];
    sm1 += (b2f(q1h0[j]) + b2f(q1l0[j])) * km0[j] +
           (b2f(q1h1[j]) + b2f(q1l1[j])) * km1[j];
  }
  sm0 += __shfl_xor(sm0, 16); sm0 += __shfl_xor(sm0, 32);
  sm1 += __shfl_xor(sm1, 16); sm1 += __shfl_xor(sm1, 32);

  const f32x4 fz = {0.f, 0.f, 0.f, 0.f};
  const f16x4 kones = {(f16)1.f, (f16)1.f, (f16)1.f, (f16)1.f};
  f32x4 oac[2][4];
#pragma unroll
  for (int g = 0; g < 2; ++g)
#pragma unroll
    for (int d = 0; d < 4; ++d) oac[g][d] = fz;
  f32x4 od0 = fz, od1 = fz;

  for (int c = 0; c < 16; ++c) {
    __syncthreads();  // buf[c&1] writes (iter c-1) + buf[(c+1)&1] reads done
    const int cb = c & 1;
    if (c < 15) STOREBUF(cb ^ 1);  // regs hold chunk c+1
    if (c < 14) LOADREG(c + 2);
#pragma unroll
    for (int t = 0; t < 4; ++t) {
      const int krow = t * 16 + l15;
      const int ksw = krow & 7;
      bf16x8 kh0 = *(const bf16x8*)&KhS[cb][krow][(lg ^ ksw) * 8];
      bf16x8 kh1 = *(const bf16x8*)&KhS[cb][krow][((4 + lg) ^ ksw) * 8];
      bf16x8 kl0 = *(const bf16x8*)&KlS[cb][krow][(lg ^ ksw) * 8];
      bf16x8 kl1 = *(const bf16x8*)&KlS[cb][krow][((4 + lg) ^ ksw) * 8];
      f32x4 a0 = fz, a1 = fz;
      a0 = MFMAB16(kh0, q0h0, a0);
      a0 = MFMAB16(kh1, q0h1, a0);
      a0 = MFMAB16(kh0, q0l0, a0);
      a0 = MFMAB16(kl0, q0h0, a0);
      a0 = MFMAB16(kh1, q0l1, a0);
      a0 = MFMAB16(kl1, q0h1, a0);
      a1 = MFMAB16(kh0, q1h0, a1);
      a1 = MFMAB16(kh1, q1h1, a1);
      a1 = MFMAB16(kh0, q1l0, a1);
      a1 = MFMAB16(kl0, q1h0, a1);
      a1 = MFMAB16(kh1, q1l1, a1);
      a1 = MFMAB16(kl1, q1h1, a1);
      f16x4 pf0, pf1;
#pragma unroll
      for (int r = 0; r < 4; ++r) {
        float v0 = a0[r];
        float e0 = (v0 > sm0) ? EXPFN(v0) : 0.f;
        pf0[r] = (f16)e0;
        float v1 = a1[r];
        float e1 = (v1 > sm1) ? EXPFN(v1) : 0.f;
        pf1[r] = (f16)e1;
      }
      od0 = MFMAPV(kones, pf0, od0);  // den: ones-column MFMA
      od1 = MFMAPV(kones, pf1, od1);
#pragma unroll
      for (int d0 = 0; d0 < 4; ++d0) {
        const int vrow = d0 * 16 + l15;
        const int vsw = vrow & 7;
        f16x4 va = *(const f16x4*)&Vs[cb][vrow]
                                     [(((t * 2 + (lg >> 1)) ^ vsw) * 8) +
                                      (lg & 1) * 4];
        oac[0][d0] = MFMAPV(va, pf0, oac[0][d0]);
        oac[1][d0] = MFMAPV(va, pf1, oac[1][d0]);
      }
    }
  }

  const float inv0 = 1.f / od0[0];  // all 4 regs equal (sum over all k)
  const float inv1 = 1.f / od1[0];
#pragma unroll
  for (int d0 = 0; d0 < 4; ++d0) {
    f16x4 o0, o1;
#pragma unroll
    for (int r = 0; r < 4; ++r) {
      o0[r] = (f16)(oac[0][d0][r] * inv0);
      o1[r] = (f16)(oac[1][d0][r] * inv1);
    }
    *(f16x4*)&Op[(size_t)(qb + l15) * DH + d0 * 16 + lg * 4] = o0;
    *(f16x4*)&Op[(size_t)(qb + 16 + l15) * DH + d0 * 16 + lg * 4] = o1;
  }
}

// ------------------------------- launcher ----------------------------------
extern "C" void kernel_launch(void* const* d_in, const int* in_sizes, int n_in,
                              void* d_out, int out_size, void* d_ws,
                              size_t ws_size, hipStream_t stream) {
  const float* x = (const float*)d_in[0];
  const float* y = (const float*)d_in[1];
  const float* qw = (const float*)d_in[2];
  const float* qb = (const float*)d_in[3];
  const float* kw = (const float*)d_in[4];
  const float* kbias = (const float*)d_in[5];
  const float* vw = (const float*)d_in[6];
  const float* vb = (const float*)d_in[7];
  const float* ow = (const float*)d_in[8];
  const float* ob = (const float*)d_in[9];
  float* out = (float*)d_out;

  char* ws = (char*)d_ws;
  const size_t WT_B = 512ull * 512 * 2;    // 512 KB
  const size_t MAT_B = 8192ull * 512 * 2;  // 8 MB
  short* qwhT = (short*)(ws + 0 * WT_B);
  short* qwlT = (short*)(ws + 1 * WT_B);
  short* kwhT = (short*)(ws + 2 * WT_B);
  short* kwlT = (short*)(ws + 3 * WT_B);
  f16* vwT = (f16*)(ws + 4 * WT_B);
  f16* owT = (f16*)(ws + 5 * WT_B);
  char* m = ws + 6 * WT_B;
  short* Qh = (short*)(m + 0 * MAT_B);
  short* Ql = (short*)(m + 1 * MAT_B);
  short* Kh = (short*)(m + 2 * MAT_B);
  short* Kl = (short*)(m + 3 * MAT_B);
  f16* Vm = (f16*)(m + 4 * MAT_B);
  short* Xh = (short*)(m + 5 * MAT_B);
  short* Xl = (short*)(m + 6 * MAT_B);
  short* Yh = (short*)(m + 7 * MAT_B);
  short* Yl = (short*)(m + 8 * MAT_B);  // 75 MB total
  // dead-buffer aliases (stream order makes these safe):
  f16* Vtr = (f16*)Xh;        // k_vtr runs after k_proj (Xh consumed)
  f16* Om = (f16*)Yh;         // k_attn runs after k_proj (Yh consumed)
  float* Kmean = (float*)Yl;  // k_kmean runs after k_proj (Yl consumed)

  hipLaunchKernelGGL(k_wt, dim3(16, 16, 4), dim3(32, 8), 0, stream, qw, kw, vw,
                     ow, qwhT, qwlT, kwhT, kwlT, vwT, owT);
  hipLaunchKernelGGL(k_split, dim3(2048, 2), dim3(256), 0, stream, x, y, Xh,
                     Xl, Yh, Yl);
  hipLaunchKernelGGL(k_proj, dim3(4, 64, 3), dim3(256), 0, stream, Xh, Xl, Yh,
                     Yl, y, qwhT, qwlT, kwhT, kwlT, vwT, qb, kbias, vb, Qh, Ql,
                     Kh, Kl, Vm);
  hipLaunchKernelGGL(k_kmean, dim3(64), dim3(256), 0, stream, Kh, Kl, Kmean);
  hipLaunchKernelGGL(k_vtr, dim3(8, 64), dim3(256), 0, stream, Vm, Vtr);
  hipLaunchKernelGGL(k_attn, dim3(64, 8), dim3(256), 0, stream, Qh, Ql, Kh, Kl,
                     Vtr, Kmean, Om);
  hipLaunchKernelGGL(k_gemm_out, dim3(4, 64), dim3(256), 0, stream, Om, owT,
                     ob, out);
}